// Round 8
// baseline (392.233 us; speedup 1.0000x reference)
//
#include <hip/hip_runtime.h>
#include <stdint.h>
#include <float.h>
#include <math.h>

using u64 = unsigned long long;
typedef float v2f __attribute__((ext_vector_type(2)));

constexpr int B_ = 2;
constexpr int NC = 512;
constexpr int NF = 8192;
constexpr int MT = 8192;

constexpr int TPB = 256;
constexpr int CF  = 16;            // coarse-rows j-chunks
constexpr int TAIL_BLOCKS = 196;   // 64 + 64 + 4 + 64

// ---- spatial grid parameters ----
constexpr int   G    = 24;         // cells per axis
constexpr int   G3   = G * G * G;  // 13824
constexpr int   G3P  = 14336;      // padded to 1024*14 for the in-block scan
constexpr float GO   = -3.0f;      // grid origin (covers +-3; outliers clamp — bound stays valid)
constexpr float GH   = 0.25f;
constexpr float GINVH= 4.0f;
constexpr float MARGIN = 1e-3f;    // >> max |d_np - d_true| (~6e-5 at |coord|<=5)

#define DEVINL __device__ __forceinline__

DEVINL float fmulrn(float a, float b){ return __fmul_rn(a,b); }
DEVINL float faddrn(float a, float b){ return __fadd_rn(a,b); }
DEVINL float fsubrn(float a, float b){ return __fsub_rn(a,b); }

// Packed fp32 helpers for the coarse brute-force body (R6-proven).
DEVINL v2f pk_mul_vs(v2f a, v2f b){ v2f d; asm("v_pk_mul_f32 %0, %1, %2" : "=v"(d) : "v"(a), "s"(b)); return d; }
DEVINL v2f pk_add_vv(v2f a, v2f b){ v2f d; asm("v_pk_add_f32 %0, %1, %2" : "=v"(d) : "v"(a), "v"(b)); return d; }
DEVINL v2f pk_add_vs(v2f a, v2f b){ v2f d; asm("v_pk_add_f32 %0, %1, %2" : "=v"(d) : "v"(a), "s"(b)); return d; }

DEVINL int cell_of(float c){
    int v = (int)floorf((c - GO) * GINVH);
    return min(max(v, 0), G - 1);
}

// ---------------------------------------------------------------------------
// prep_build, 12 blocks x 1024 threads:
//   bx 0..3 : build one grid each (0=tgt b0, 1=tgt b1, 2=fine b0, 3=fine b1):
//             LDS histogram -> in-block exclusive scan -> scatter to
//             spts (x,y,z,qq) + sj (orig index) + global ofs[G3+1].
//   bx 4..11: pack tgtp / coarsep pair-interleaved arrays for the coarse
//             brute-force body (same layout/arith as R6 — bit-exact lineage).
// ---------------------------------------------------------------------------
__global__ __launch_bounds__(1024) void prep_build(
    const float* __restrict__ coarse, const float* __restrict__ fine,
    const float* __restrict__ tgt,
    float4* __restrict__ spts, int* __restrict__ sjall, int* __restrict__ ofsall,
    int* __restrict__ pcell,
    float* __restrict__ tgtp, float* __restrict__ coarsep,
    unsigned* __restrict__ counter)
{
#pragma clang fp contract(off)
    const int bx = blockIdx.x, tid = threadIdx.x;
    if (bx >= 4) {
        int idx = (bx - 4) * 1024 + tid;          // pair index 0..8191
        if (idx == 0) *counter = 0;
        {   // tgt pairs (B_*MT/2 = 8192)
            const float* p = tgt + (size_t)idx * 6;
            float x0=p[0],y0=p[1],z0=p[2],x1=p[3],y1=p[4],z1=p[5];
            float* o = tgtp + (size_t)idx * 8;
            o[0]=x0; o[1]=x1; o[2]=y0; o[3]=y1; o[4]=z0; o[5]=z1;
            o[6]=(x0*x0+y0*y0)+z0*z0;  o[7]=(x1*x1+y1*y1)+z1*z1;
        }
        if (idx < B_ * NC / 2) {
            const float* p = coarse + (size_t)idx * 6;
            float x0=p[0],y0=p[1],z0=p[2],x1=p[3],y1=p[4],z1=p[5];
            float* o = coarsep + (size_t)idx * 8;
            o[0]=x0; o[1]=x1; o[2]=y0; o[3]=y1; o[4]=z0; o[5]=z1;
            o[6]=(x0*x0+y0*y0)+z0*z0;  o[7]=(x1*x1+y1*y1)+z1*z1;
        }
        return;
    }

    // ---- grid build ----
    __shared__ int cnt[G3P];
    __shared__ int wsum[16];
    const int set = bx;
    const float* pts = (set < 2 ? tgt : fine) + (size_t)(set & 1) * 8192 * 3;
    float4* sp = spts  + (size_t)set * 8192;
    int*    sj = sjall + (size_t)set * 8192;
    int*    of = ofsall + (size_t)set * (G3 + 1);
    int*    pc = pcell + (size_t)set * 8192;

    for (int i = tid; i < G3P; i += 1024) cnt[i] = 0;
    __syncthreads();
    for (int i = tid; i < 8192; i += 1024) {
        const float* p = pts + (size_t)i * 3;
        int c = (cell_of(p[0]) * G + cell_of(p[1])) * G + cell_of(p[2]);
        pc[i] = c;
        atomicAdd(&cnt[c], 1);
    }
    __syncthreads();
    // exclusive scan over G3P cells: 14 serial per thread + hierarchical scan
    const int lane = tid & 63, wid = tid >> 6;
    const int base = tid * 14;
    int loc[14]; int s = 0;
    #pragma unroll
    for (int k = 0; k < 14; ++k) { loc[k] = s; s += cnt[base + k]; }
    int v = s;
    for (int o = 1; o < 64; o <<= 1) { int t = __shfl_up(v, o); if (lane >= o) v += t; }
    if (lane == 63) wsum[wid] = v;
    __syncthreads();
    if (wid == 0 && lane < 16) {
        int w = wsum[lane];
        for (int o = 1; o < 16; o <<= 1) { int t = __shfl_up(w, o); if (lane >= o) w += t; }
        wsum[lane] = w;   // inclusive wave sums
    }
    __syncthreads();
    int excl = ((wid == 0) ? 0 : wsum[wid - 1]) + (v - s);
    #pragma unroll
    for (int k = 0; k < 14; ++k) {
        int c = base + k;
        int st = excl + loc[k];
        if (c < G3) of[c] = st;
        cnt[c] = st;                  // starts, consumed by scatter atomics
    }
    if (tid == 0) of[G3] = 8192;
    __syncthreads();
    for (int i = tid; i < 8192; i += 1024) {
        int c = pc[i];
        int dst = atomicAdd(&cnt[c], 1);
        const float* p = pts + (size_t)i * 3;
        float a = p[0], b = p[1], cc = p[2];
        sp[dst] = make_float4(a, b, cc,
                              faddrn(faddrn(fmulrn(a,a), fmulrn(b,b)), fmulrn(cc,cc)));
        sj[dst] = i;
    }
}

// ---------------------------------------------------------------------------
// grid_nn: exact-d nearest neighbor via expanding ring search.
// d per candidate is the bit-exact numpy fp32 sequence (R1-R6 verified):
//   d = max(fl(fl(xx+qq) - fl(2*fl(fl(fl(x0q0)+fl(x1q1))+fl(x2q2)))), 0)
// Pruning: cells at Chebyshev ring >= r have true sqdist >= ((r-1)*h)^2
// (valid under edge clamping — clamp is monotone, so box-distance lower-bounds
// hold); stop when best + MARGIN <= ((r-1)h)^2. Pruned j then satisfy
// d_np(j) > best strictly => numpy min value AND first-index tie-break
// preserved by the packed (d,j) u64 min over all scanned candidates.
// ---------------------------------------------------------------------------
template<bool ARGMIN>
DEVINL u64 grid_nn(float q0, float q1, float q2,
                   const float4* __restrict__ sp, const int* __restrict__ sj,
                   const int* __restrict__ ofs)
{
    float xx = faddrn(faddrn(fmulrn(q0,q0), fmulrn(q1,q1)), fmulrn(q2,q2));
    const int cx = cell_of(q0), cy = cell_of(q1), cz = cell_of(q2);
    u64 best = ~0ull;
    float bestf = FLT_MAX;

    auto scan_cell = [&](int x, int y, int z) {
        int c = (x * G + y) * G + z;
        int s = ofs[c], e = ofs[c + 1];
        int k = s;
        for (; k + 4 <= e; k += 4) {               // 4 gathers in flight
            float4 p0 = sp[k], p1 = sp[k+1], p2 = sp[k+2], p3 = sp[k+3];
            int j0=0, j1=0, j2=0, j3=0;
            if (ARGMIN) { j0 = sj[k]; j1 = sj[k+1]; j2 = sj[k+2]; j3 = sj[k+3]; }
            float4 ps[4] = {p0, p1, p2, p3};
            int    js[4] = {j0, j1, j2, j3};
            #pragma unroll
            for (int u = 0; u < 4; ++u) {
                float4 p = ps[u];
                float xy = faddrn(faddrn(fmulrn(q0,p.x), fmulrn(q1,p.y)), fmulrn(q2,p.z));
                float t  = faddrn(xx, p.w);
                float d  = fsubrn(t, fmulrn(2.0f, xy));
                d = fmaxf(d, 0.0f);
                if (ARGMIN) {
                    u64 pk = ((u64)__float_as_uint(d) << 32) | (unsigned)js[u];
                    best = pk < best ? pk : best;
                }
                bestf = fminf(bestf, d);
            }
        }
        for (; k < e; ++k) {
            float4 p = sp[k];
            float xy = faddrn(faddrn(fmulrn(q0,p.x), fmulrn(q1,p.y)), fmulrn(q2,p.z));
            float t  = faddrn(xx, p.w);
            float d  = fsubrn(t, fmulrn(2.0f, xy));
            d = fmaxf(d, 0.0f);
            if (ARGMIN) {
                u64 pk = ((u64)__float_as_uint(d) << 32) | (unsigned)sj[k];
                best = pk < best ? pk : best;
            }
            bestf = fminf(bestf, d);
        }
    };

    for (int r = 0; r < G; ++r) {
        if (r >= 2) {
            float rb = (float)(r - 1) * GH;
            if (bestf + MARGIN <= rb * rb) break;
        }
        int xlo = max(cx - r, 0), xhi = min(cx + r, G - 1);
        int ylo = max(cy - r, 0), yhi = min(cy + r, G - 1);
        int zlo = max(cz - r, 0), zhi = min(cz + r, G - 1);
        for (int x = xlo; x <= xhi; ++x) {
            bool xe = (x == cx - r) || (x == cx + r);
            for (int y = ylo; y <= yhi; ++y) {
                bool face = xe || (y == cy - r) || (y == cy + r);
                if (face) {
                    for (int z = zlo; z <= zhi; ++z) scan_cell(x, y, z);
                } else {
                    if (cz - r >= 0)     scan_cell(x, y, cz - r);
                    if (cz + r <= G - 1) scan_cell(x, y, cz + r);
                }
            }
        }
    }
    if (ARGMIN) return best;
    return (u64)__float_as_uint(bestf);
}

// ---------------------------------------------------------------------------
// Coarse brute-force body (R6 s_load + pk-asm structure, value-only).
// ---------------------------------------------------------------------------
DEVINL void pairmin_val(const float* __restrict__ P, const v2f* __restrict__ Qp,
                        int nP, int nQpairsB, int b, int row_base,
                        int jp0, int jplen, int chunk, int nRowsTot,
                        unsigned* __restrict__ outVal)
{
#pragma clang fp contract(off)
    const int tid = threadIdx.x;
    const int row = row_base + tid;
    const float* p = P + ((size_t)b * nP + row) * 3;
    float a0 = p[0], a1 = p[1], a2 = p[2];
    v2f vax = {-2.0f*a0, -2.0f*a0}, vay = {-2.0f*a1, -2.0f*a1}, vaz = {-2.0f*a2, -2.0f*a2};
    float xx = (a0*a0 + a1*a1) + a2*a2;
    v2f vxx = {xx, xx};
    float db0 = FLT_MAX, db1 = FLT_MAX;

    const v2f* Q = Qp + ((size_t)b * nQpairsB + jp0) * 4;
    v2f qx = Q[0], qy = Q[1], qz = Q[2], qw = Q[3];   // uniform -> s_load
    for (int k = 0; k < jplen; ++k) {
        const v2f* Qn = Q + (size_t)(k + 1) * 4;
        v2f nx = Qn[0], ny = Qn[1], nz = Qn[2], nw = Qn[3];  // (+32B overrun ok)
        v2f m0  = pk_mul_vs(vax, qx);
        v2f m1  = pk_mul_vs(vay, qy);
        v2f m2  = pk_mul_vs(vaz, qz);
        v2f s01 = pk_add_vv(m0, m1);
        v2f sxy = pk_add_vv(s01, m2);     // == -(2*xy) bitwise
        v2f tt  = pk_add_vs(vxx, qw);
        v2f d   = pk_add_vv(tt, sxy);     // == (xx+qq) - 2*xy bitwise
        db0 = __builtin_amdgcn_fmed3f(d.x, 0.0f, db0);
        db1 = __builtin_amdgcn_fmed3f(d.y, 0.0f, db1);
        qx = nx; qy = ny; qz = nz; qw = nw;
    }
    outVal[(size_t)chunk * nRowsTot + (size_t)b * nP + row] =
        __float_as_uint(fminf(db0, db1));
}

// ---------------------------------------------------------------------------
// pair_all, 256 blocks x 256:
//  [0,  64) fine-rows NN : query=fine[g], grid=tgt set b, ARGMIN -> pfr[g]
//  [64,128) fine-cols NN : query=tgt[g],  grid=fine set b, value -> pfc[g]
//  [128,192) coarse-rows brute: 16 ch x 2 yb x 2 b over tgtp -> pcr
//  [192,256) coarse-cols brute: 32 yb x 2 b over coarsep     -> pcc
// ---------------------------------------------------------------------------
__global__ __launch_bounds__(TPB) void pair_all(
    const float* __restrict__ coarse, const float* __restrict__ fine,
    const float* __restrict__ tgt,
    const float4* __restrict__ spts, const int* __restrict__ sjall,
    const int* __restrict__ ofsall,
    const v2f* __restrict__ tgtp, const v2f* __restrict__ coarsep,
    u64* __restrict__ pfr, unsigned* __restrict__ pfc,
    unsigned* __restrict__ pcr, unsigned* __restrict__ pcc)
{
    const int bx = blockIdx.x, tid = threadIdx.x;
    if (bx < 64) {
        int g = bx * TPB + tid;            // 0..16383
        int b = g >> 13;
        const float* q = fine + (size_t)g * 3;
        pfr[g] = grid_nn<true>(q[0], q[1], q[2],
                               spts + (size_t)b * 8192, sjall + (size_t)b * 8192,
                               ofsall + (size_t)b * (G3 + 1));
    } else if (bx < 128) {
        int g = (bx - 64) * TPB + tid;
        int b = g >> 13;
        const float* q = tgt + (size_t)g * 3;
        int set = 2 + b;
        u64 r = grid_nn<false>(q[0], q[1], q[2],
                               spts + (size_t)set * 8192, sjall + (size_t)set * 8192,
                               ofsall + (size_t)set * (G3 + 1));
        pfc[g] = (unsigned)r;
    } else if (bx < 192) {
        int i = bx - 128;
        int chunk = i & 15, yb = (i >> 4) & 1, b = i >> 5;
        pairmin_val(coarse, tgtp, NC, MT/2, b, yb*TPB, chunk*256, 256,
                    chunk, B_*NC, pcr);
    } else {
        int i = bx - 192;
        int yb = i & 31, b = i >> 5;
        pairmin_val(tgt, coarsep, MT, NC/2, b, yb*TPB, 0, 256,
                    0, B_*MT, pcc);
    }
}

// ---------------------------------------------------------------------------
// tail_all: gather + stats + wedge volumes + reductions + final combine.
// Fine results are now single-slice (no chunk reduce); coarse-rows keeps 16.
// ---------------------------------------------------------------------------
__global__ __launch_bounds__(TPB) void tail_all(
    const float* __restrict__ fine, const float* __restrict__ tgt,
    const u64* __restrict__ pfr, const unsigned* __restrict__ pfc,
    const unsigned* __restrict__ pcr, const unsigned* __restrict__ pcc,
    double* __restrict__ bs, unsigned* __restrict__ counter,
    float* __restrict__ out)
{
    __shared__ float sp[TPB + 2][3], yp[TPB + 2][3];
    __shared__ double redw[4][9];
    __shared__ double lred[4][13];
    __shared__ int lastflag;
    const int bx = blockIdx.x, tid = threadIdx.x;
    const int wave = tid >> 6, lane = tid & 63;

    double v_s = 0, v_d2f = 0, v_d1c = 0, v_d2c = 0, v_yd2 = 0, v_zs = 0, v_zt = 0;
    double vs = 0, vt = 0;
    int role_b = 0;

    if (bx < 64) {                              // ---- fine-rows ----
        const int base = bx * TPB;
        const int g = base + tid;
        const int b = base >> 13;  role_b = b;
        u64 best = pfr[g];
        float d1 = __uint_as_float((unsigned)(best >> 32));
        int idx  = (int)(best & 0xffffffffULL);
        float s = sqrtf(fmaxf(d1, 1e-12f));
        const float* y  = tgt  + ((size_t)b * MT + idx) * 3;
        const float* sr = fine + (size_t)g * 3;
        float y0 = y[0],  y1 = y[1],  y2 = y[2];
        float s0 = sr[0], s1 = sr[1], s2 = sr[2];
        yp[tid][0] = y0; yp[tid][1] = y1; yp[tid][2] = y2;
        sp[tid][0] = s0; sp[tid][1] = s1; sp[tid][2] = s2;
        const int base_b = base & (NF - 1);
        if (tid < 2 && base_b + TPB + tid < NF) {        // halo rows
            int g2 = base + TPB + tid;
            u64 b2 = pfr[g2];
            int i2 = (int)(b2 & 0xffffffffULL);
            const float* yh = tgt  + ((size_t)b * MT + i2) * 3;
            const float* sh = fine + (size_t)g2 * 3;
            #pragma unroll
            for (int k = 0; k < 3; ++k) { yp[TPB + tid][k] = yh[k]; sp[TPB + tid][k] = sh[k]; }
        }
        __syncthreads();
        v_s = s;
        float yd = s1 - y1;
        v_yd2 = (double)(yd * yd);
        v_zs  = (double)(s2 * s2);
        v_zt  = (double)(y2 * y2);
        int rb = base_b + tid;
        if (rb <= NF - 3) {          // same f32 exprs as the verified R3 kernel
            {
                const float* a = sp[tid]; const float* c = sp[tid+1]; const float* e = sp[tid+2];
                float c0 = a[1]*c[2] - a[2]*c[1];
                float c1 = a[2]*c[0] - a[0]*c[2];
                float c2 = a[0]*c[1] - a[1]*c[0];
                vs = (double)(c0*e[0] + c1*e[1] + c2*e[2]);
            }
            {
                const float* a = yp[tid]; const float* c = yp[tid+1]; const float* e = yp[tid+2];
                float c0 = a[1]*c[2] - a[2]*c[1];
                float c1 = a[2]*c[0] - a[0]*c[2];
                float c2 = a[0]*c[1] - a[1]*c[0];
                vt = (double)(c0*e[0] + c1*e[1] + c2*e[2]);
            }
        }
    } else if (bx < 128) {                      // ---- fine-cols ----
        const int g = (bx - 64) * TPB + tid;
        v_d2f = (double)sqrtf(fmaxf(__uint_as_float(pfc[g]), 1e-12f));
    } else if (bx < 132) {                      // ---- coarse-rows ----
        const int g = (bx - 128) * TPB + tid;
        unsigned best = pcr[g];
        #pragma unroll
        for (int c = 1; c < CF; ++c) best = min(best, pcr[(size_t)c * (B_ * NC) + g]);
        v_d1c = (double)sqrtf(fmaxf(__uint_as_float(best), 1e-12f));
    } else {                                    // ---- coarse-cols ----
        const int g = (bx - 132) * TPB + tid;
        v_d2c = (double)sqrtf(fmaxf(__uint_as_float(pcc[g]), 1e-12f));
    }

    // block reduce 9 values
    double r9[9] = {v_s, v_d2f, v_d1c, v_d2c, v_yd2, v_zs, v_zt, vs, vt};
    for (int o = 32; o; o >>= 1) {
        #pragma unroll
        for (int k = 0; k < 9; ++k) r9[k] += __shfl_down(r9[k], o);
    }
    if (lane == 0) {
        #pragma unroll
        for (int k = 0; k < 9; ++k) redw[wave][k] = r9[k];
    }
    __syncthreads();
    if (tid == 0) {
        double t9[9];
        #pragma unroll
        for (int k = 0; k < 9; ++k)
            t9[k] = redw[0][k] + redw[1][k] + redw[2][k] + redw[3][k];
        double* o = bs + (size_t)bx * 16;
        #pragma unroll
        for (int k = 0; k < 16; ++k) o[k] = 0.0;
        o[0] = t9[0]; o[1] = t9[1]; o[2] = t9[2]; o[3] = t9[3]; o[4] = t9[4];
        o[5 + role_b]  = t9[5];   // zs
        o[7 + role_b]  = t9[6];   // zt
        o[9 + role_b]  = t9[7];   // vs
        o[11 + role_b] = t9[8];   // vt
        __threadfence();
        unsigned old = atomicAdd(counter, 1u);
        lastflag = (old == TAIL_BLOCKS - 1);
    }
    __syncthreads();
    if (!lastflag) return;

    // ---- final combine (last block only) ----
    __threadfence();
    double c13[13];
    if (tid < TAIL_BLOCKS) {
        const double* p = bs + (size_t)tid * 16;
        #pragma unroll
        for (int k = 0; k < 13; ++k) c13[k] = p[k];
    } else {
        #pragma unroll
        for (int k = 0; k < 13; ++k) c13[k] = 0.0;
    }
    for (int o = 32; o; o >>= 1) {
        #pragma unroll
        for (int k = 0; k < 13; ++k) c13[k] += __shfl_down(c13[k], o);
    }
    if (lane == 0) {
        #pragma unroll
        for (int k = 0; k < 13; ++k) lred[wave][k] = c13[k];
    }
    __syncthreads();
    if (tid == 0) {
        double S[13];
        #pragma unroll
        for (int k = 0; k < 13; ++k)
            S[k] = lred[0][k] + lred[1][k] + lred[2][k] + lred[3][k];
        double m_d1f = S[0] / (double)(B_ * NF);
        double m_d2f = S[1] / (double)(B_ * MT);
        double m_d1c = S[2] / (double)(B_ * NC);
        double m_d2c = S[3] / (double)(B_ * MT);
        double loss_align_fine   = 0.5 * (m_d1f + m_d2f);
        double loss_align_coarse = 0.5 * (m_d1c + m_d2c);
        double loss_ref = S[4] / (double)(B_ * NF);
        double loss_rot = 0.0, loss_geo = 0.0;
        for (int b = 0; b < B_; ++b) {
            double dn = sqrt(S[5 + b]) - sqrt(S[7 + b]);
            loss_rot += dn * dn;
            double dv = (S[9 + b] - S[11 + b]) / 6.0;
            loss_geo += dv * dv;
        }
        loss_rot /= (double)B_;
        loss_geo /= (double)B_;
        out[0] = (float)(loss_rot + loss_ref + loss_align_coarse + loss_align_fine + loss_geo);
    }
}

extern "C" void kernel_launch(void* const* d_in, const int* in_sizes, int n_in,
                              void* d_out, int out_size, void* d_ws, size_t ws_size,
                              hipStream_t stream)
{
    const float* src_coarse = (const float*)d_in[0];
    const float* src_fine   = (const float*)d_in[1];
    const float* tgt        = (const float*)d_in[2];
    float* out = (float*)d_out;
    char*  ws  = (char*)d_ws;

    // ws layout (bytes) — everything written before read, no init needed.
    // Brute-force prefetch overruns (<=32B) land in the next region: harmless.
    //   [0,       131072)  u64 pfr[16384]         fine-rows (d,j)
    //   [131072,  196608)  u32 pfc[16384]         fine-cols min d
    //   [196608,  262144)  u32 pcr[16][1024]      coarse-rows partials
    //   [262144,  327680)  u32 pcc[16384]         coarse-cols
    //   [327680,  589824)  float tgtp[8192*8]     pair-interleaved
    //   [589824,  606208)  float coarsep[512*8]
    //   [606208,  1130496) float4 spts[4][8192]   sorted grid points (x,y,z,qq)
    //   [1130496, 1261568) int sj[4][8192]        original indices
    //   [1261568, 1482768) int ofs[4][G3+1]       cell offsets
    //   [1482768, 1613840) int pcell[4][8192]     build scratch
    //   [1613840, 1638928) double bs[196][16]
    //   [1638928, 1638932) u32 counter            (zeroed by prep_build)
    u64*      pfr     = (u64*)(ws);
    unsigned* pfc     = (unsigned*)(ws + 131072);
    unsigned* pcr     = (unsigned*)(ws + 196608);
    unsigned* pcc     = (unsigned*)(ws + 262144);
    float*    tgtp    = (float*)(ws + 327680);
    float*    coarsep = (float*)(ws + 589824);
    float4*   spts    = (float4*)(ws + 606208);
    int*      sjall   = (int*)(ws + 1130496);
    int*      ofsall  = (int*)(ws + 1261568);
    int*      pcell   = (int*)(ws + 1482768);
    double*   bs      = (double*)(ws + 1613840);
    unsigned* counter = (unsigned*)(ws + 1638928);

    prep_build<<<dim3(12), 1024, 0, stream>>>(
        src_coarse, src_fine, tgt, spts, sjall, ofsall, pcell,
        tgtp, coarsep, counter);
    pair_all<<<dim3(256), TPB, 0, stream>>>(
        src_coarse, src_fine, tgt, spts, sjall, ofsall,
        (const v2f*)tgtp, (const v2f*)coarsep, pfr, pfc, pcr, pcc);
    tail_all<<<dim3(TAIL_BLOCKS), TPB, 0, stream>>>(
        src_fine, tgt, pfr, pfc, pcr, pcc, bs, counter, out);
}

// Round 9
// 238.511 us; speedup vs baseline: 1.6445x; 1.6445x over previous
//
#include <hip/hip_runtime.h>
#include <stdint.h>
#include <float.h>
#include <math.h>

using u64 = unsigned long long;
typedef float v2f __attribute__((ext_vector_type(2)));

constexpr int B_ = 2;
constexpr int NC = 512;
constexpr int NF = 8192;
constexpr int MT = 8192;

constexpr int TPB = 256;           // tail/prep block size
constexpr int BT  = 64;            // pair_all block size (1 wave)
constexpr int CF  = 16;            // coarse-rows j-chunks
constexpr int TAIL_BLOCKS = 196;   // 64 + 64 + 4 + 64

// ---- spatial grid parameters ----
constexpr int   G    = 24;
constexpr int   G3   = G * G * G;  // 13824
constexpr int   G3P  = 14336;      // padded for the in-block scan
constexpr float GO   = -3.0f;
constexpr float GH   = 0.25f;
constexpr float GINVH= 4.0f;
constexpr float MARGIN = 1e-3f;    // >> max |d_np - d_true| (~6e-5 at |coord|<=5)

#define DEVINL __device__ __forceinline__

DEVINL float fmulrn(float a, float b){ return __fmul_rn(a,b); }
DEVINL float faddrn(float a, float b){ return __fadd_rn(a,b); }
DEVINL float fsubrn(float a, float b){ return __fsub_rn(a,b); }

DEVINL v2f pk_mul_vs(v2f a, v2f b){ v2f d; asm("v_pk_mul_f32 %0, %1, %2" : "=v"(d) : "v"(a), "s"(b)); return d; }
DEVINL v2f pk_add_vv(v2f a, v2f b){ v2f d; asm("v_pk_add_f32 %0, %1, %2" : "=v"(d) : "v"(a), "v"(b)); return d; }
DEVINL v2f pk_add_vs(v2f a, v2f b){ v2f d; asm("v_pk_add_f32 %0, %1, %2" : "=v"(d) : "v"(a), "s"(b)); return d; }

DEVINL int cell_of(float c){
    int v = (int)floorf((c - GO) * GINVH);
    return min(max(v, 0), G - 1);
}

// ---------------------------------------------------------------------------
// prep_build (unchanged from R8 — verified): 4 grid-build blocks + 8 pack
// blocks. Grids: sorted (x,y,z,qq) + orig index + cell offsets. qq uses the
// bit-exact numpy fp32 op sequence.
// ---------------------------------------------------------------------------
__global__ __launch_bounds__(1024) void prep_build(
    const float* __restrict__ coarse, const float* __restrict__ fine,
    const float* __restrict__ tgt,
    float4* __restrict__ spts, int* __restrict__ sjall, int* __restrict__ ofsall,
    int* __restrict__ pcell,
    float* __restrict__ tgtp, float* __restrict__ coarsep,
    unsigned* __restrict__ counter)
{
#pragma clang fp contract(off)
    const int bx = blockIdx.x, tid = threadIdx.x;
    if (bx >= 4) {
        int idx = (bx - 4) * 1024 + tid;          // pair index 0..8191
        if (idx == 0) *counter = 0;
        {
            const float* p = tgt + (size_t)idx * 6;
            float x0=p[0],y0=p[1],z0=p[2],x1=p[3],y1=p[4],z1=p[5];
            float* o = tgtp + (size_t)idx * 8;
            o[0]=x0; o[1]=x1; o[2]=y0; o[3]=y1; o[4]=z0; o[5]=z1;
            o[6]=(x0*x0+y0*y0)+z0*z0;  o[7]=(x1*x1+y1*y1)+z1*z1;
        }
        if (idx < B_ * NC / 2) {
            const float* p = coarse + (size_t)idx * 6;
            float x0=p[0],y0=p[1],z0=p[2],x1=p[3],y1=p[4],z1=p[5];
            float* o = coarsep + (size_t)idx * 8;
            o[0]=x0; o[1]=x1; o[2]=y0; o[3]=y1; o[4]=z0; o[5]=z1;
            o[6]=(x0*x0+y0*y0)+z0*z0;  o[7]=(x1*x1+y1*y1)+z1*z1;
        }
        return;
    }

    __shared__ int cnt[G3P];
    __shared__ int wsum[16];
    const int set = bx;   // 0=tgt b0, 1=tgt b1, 2=fine b0, 3=fine b1
    const float* pts = (set < 2 ? tgt : fine) + (size_t)(set & 1) * 8192 * 3;
    float4* sp = spts  + (size_t)set * 8192;
    int*    sj = sjall + (size_t)set * 8192;
    int*    of = ofsall + (size_t)set * (G3 + 1);
    int*    pc = pcell + (size_t)set * 8192;

    for (int i = tid; i < G3P; i += 1024) cnt[i] = 0;
    __syncthreads();
    for (int i = tid; i < 8192; i += 1024) {
        const float* p = pts + (size_t)i * 3;
        int c = (cell_of(p[0]) * G + cell_of(p[1])) * G + cell_of(p[2]);
        pc[i] = c;
        atomicAdd(&cnt[c], 1);
    }
    __syncthreads();
    const int lane = tid & 63, wid = tid >> 6;
    const int base = tid * 14;
    int loc[14]; int s = 0;
    #pragma unroll
    for (int k = 0; k < 14; ++k) { loc[k] = s; s += cnt[base + k]; }
    int v = s;
    for (int o = 1; o < 64; o <<= 1) { int t = __shfl_up(v, o); if (lane >= o) v += t; }
    if (lane == 63) wsum[wid] = v;
    __syncthreads();
    if (wid == 0 && lane < 16) {
        int w = wsum[lane];
        for (int o = 1; o < 16; o <<= 1) { int t = __shfl_up(w, o); if (lane >= o) w += t; }
        wsum[lane] = w;
    }
    __syncthreads();
    int excl = ((wid == 0) ? 0 : wsum[wid - 1]) + (v - s);
    #pragma unroll
    for (int k = 0; k < 14; ++k) {
        int c = base + k;
        int st = excl + loc[k];
        if (c < G3) of[c] = st;
        cnt[c] = st;
    }
    if (tid == 0) of[G3] = 8192;
    __syncthreads();
    for (int i = tid; i < 8192; i += 1024) {
        int c = pc[i];
        int dst = atomicAdd(&cnt[c], 1);
        const float* p = pts + (size_t)i * 3;
        float a = p[0], b = p[1], cc = p[2];
        sp[dst] = make_float4(a, b, cc,
                              faddrn(faddrn(fmulrn(a,a), fmulrn(b,b)), fmulrn(cc,cc)));
        sj[dst] = i;
    }
}

// ---------------------------------------------------------------------------
// grid_nn: exact-d NN via expanding ring search over CONTIGUOUS COLUMN RANGES
// (cell index = (x*G+y)*G+z, so a z-run is contiguous in the sorted array —
// one ofs pair per column instead of per cell). d per candidate is the
// bit-exact numpy fp32 sequence (R1-R8 verified). Pruning identical to R8
// (verified): stop after ring r when bestf + MARGIN <= ((r-1)h)^2; clamping
// preserves the lower bound; min over scanned set is order/重scan-idempotent,
// so the packed (d,j) u64 min preserves numpy's value AND first-index ties.
// ---------------------------------------------------------------------------
template<bool ARGMIN>
DEVINL u64 grid_nn(float4 qp,
                   const float4* __restrict__ sp, const int* __restrict__ sj,
                   const int* __restrict__ ofs)
{
    const float q0 = qp.x, q1 = qp.y, q2 = qp.z, xx = qp.w;
    const int cx = cell_of(q0), cy = cell_of(q1), cz = cell_of(q2);
    u64 best = ~0ull;
    float bestf = FLT_MAX;

    auto scan_range = [&](int s, int e) {
        int k = s;
        for (; k + 4 <= e; k += 4) {               // 4 gathers in flight
            float4 p0 = sp[k], p1 = sp[k+1], p2 = sp[k+2], p3 = sp[k+3];
            int js[4] = {0,0,0,0};
            if (ARGMIN) { js[0] = sj[k]; js[1] = sj[k+1]; js[2] = sj[k+2]; js[3] = sj[k+3]; }
            float4 ps[4] = {p0, p1, p2, p3};
            #pragma unroll
            for (int u = 0; u < 4; ++u) {
                float4 p = ps[u];
                float xy = faddrn(faddrn(fmulrn(q0,p.x), fmulrn(q1,p.y)), fmulrn(q2,p.z));
                float t  = faddrn(xx, p.w);
                float d  = fsubrn(t, fmulrn(2.0f, xy));
                d = fmaxf(d, 0.0f);
                if (ARGMIN) {
                    u64 pk = ((u64)__float_as_uint(d) << 32) | (unsigned)js[u];
                    best = pk < best ? pk : best;
                }
                bestf = fminf(bestf, d);
            }
        }
        for (; k < e; ++k) {
            float4 p = sp[k];
            float xy = faddrn(faddrn(fmulrn(q0,p.x), fmulrn(q1,p.y)), fmulrn(q2,p.z));
            float t  = faddrn(xx, p.w);
            float d  = fsubrn(t, fmulrn(2.0f, xy));
            d = fmaxf(d, 0.0f);
            if (ARGMIN) {
                u64 pk = ((u64)__float_as_uint(d) << 32) | (unsigned)sj[k];
                best = pk < best ? pk : best;
            }
            bestf = fminf(bestf, d);
        }
    };

    for (int r = 0; r < G; ++r) {
        if (r >= 2) {
            float rb = (float)(r - 1) * GH;
            if (bestf + MARGIN <= rb * rb) break;
        }
        int xlo = max(cx - r, 0), xhi = min(cx + r, G - 1);
        int ylo = max(cy - r, 0), yhi = min(cy + r, G - 1);
        int zlo = max(cz - r, 0), zhi = min(cz + r, G - 1);
        for (int x = xlo; x <= xhi; ++x) {
            bool xe = (x == cx - r) || (x == cx + r);
            for (int y = ylo; y <= yhi; ++y) {
                int cb = (x * G + y) * G;
                if (xe || (y == cy - r) || (y == cy + r)) {
                    scan_range(ofs[cb + zlo], ofs[cb + zhi + 1]);   // whole z-run, contiguous
                } else {
                    if (cz - r >= 0)     { int c = cb + cz - r; scan_range(ofs[c], ofs[c+1]); }
                    if (cz + r <= G - 1) { int c = cb + cz + r; scan_range(ofs[c], ofs[c+1]); }
                }
            }
        }
    }
    if (ARGMIN) return best;
    return (u64)__float_as_uint(bestf);
}

// ---------------------------------------------------------------------------
// Coarse brute-force body (R6 s_load + pk-asm, value-only) — 64-thread rows.
// ---------------------------------------------------------------------------
DEVINL void pairmin_val(const float* __restrict__ P, const v2f* __restrict__ Qp,
                        int nP, int nQpairsB, int b, int row_base,
                        int jp0, int jplen, int chunk, int nRowsTot,
                        unsigned* __restrict__ outVal)
{
#pragma clang fp contract(off)
    const int tid = threadIdx.x;
    const int row = row_base + tid;
    const float* p = P + ((size_t)b * nP + row) * 3;
    float a0 = p[0], a1 = p[1], a2 = p[2];
    v2f vax = {-2.0f*a0, -2.0f*a0}, vay = {-2.0f*a1, -2.0f*a1}, vaz = {-2.0f*a2, -2.0f*a2};
    float xx = (a0*a0 + a1*a1) + a2*a2;
    v2f vxx = {xx, xx};
    float db0 = FLT_MAX, db1 = FLT_MAX;

    const v2f* Q = Qp + ((size_t)b * nQpairsB + jp0) * 4;
    v2f qx = Q[0], qy = Q[1], qz = Q[2], qw = Q[3];   // uniform -> s_load
    for (int k = 0; k < jplen; ++k) {
        const v2f* Qn = Q + (size_t)(k + 1) * 4;
        v2f nx = Qn[0], ny = Qn[1], nz = Qn[2], nw = Qn[3];  // (+32B overrun ok)
        v2f m0  = pk_mul_vs(vax, qx);
        v2f m1  = pk_mul_vs(vay, qy);
        v2f m2  = pk_mul_vs(vaz, qz);
        v2f s01 = pk_add_vv(m0, m1);
        v2f sxy = pk_add_vv(s01, m2);     // == -(2*xy) bitwise
        v2f tt  = pk_add_vs(vxx, qw);
        v2f d   = pk_add_vv(tt, sxy);     // == (xx+qq) - 2*xy bitwise
        db0 = __builtin_amdgcn_fmed3f(d.x, 0.0f, db0);
        db1 = __builtin_amdgcn_fmed3f(d.y, 0.0f, db1);
        qx = nx; qy = ny; qz = nz; qw = nw;
    }
    outVal[(size_t)chunk * nRowsTot + (size_t)b * nP + row] =
        __float_as_uint(fminf(db0, db1));
}

// ---------------------------------------------------------------------------
// pair_all, 1024 blocks x 64 threads (NN first):
//  [0,   256) fine-rows NN : queries = fine points IN FINE'S SORTED ORDER
//                            (coherent waves), grid = tgt, ARGMIN -> pfr[orig]
//  [256, 512) fine-cols NN : queries = tgt sorted, grid = fine -> pfc[orig]
//  [512, 768) coarse-rows brute: 16 ch x 8 yb x 2 b -> pcr
//  [768,1024) coarse-cols brute: 128 yb x 2 b       -> pcc
// ---------------------------------------------------------------------------
__global__ __launch_bounds__(BT) void pair_all(
    const float* __restrict__ coarse, const float* __restrict__ tgt,
    const float4* __restrict__ spts, const int* __restrict__ sjall,
    const int* __restrict__ ofsall,
    const v2f* __restrict__ tgtp, const v2f* __restrict__ coarsep,
    u64* __restrict__ pfr, unsigned* __restrict__ pfc,
    unsigned* __restrict__ pcr, unsigned* __restrict__ pcc)
{
    const int bx = blockIdx.x, tid = threadIdx.x;
    if (bx < 256) {
        int k  = bx * BT + tid;            // 0..16383 over sorted fine points
        int b  = k >> 13, kl = k & 8191;
        int sq = 2 + b;                    // fine set (query), tgt set = b (grid)
        float4 qp = spts[(size_t)sq * 8192 + kl];
        int    qi = sjall[(size_t)sq * 8192 + kl];
        u64 r = grid_nn<true>(qp, spts + (size_t)b * 8192, sjall + (size_t)b * 8192,
                              ofsall + (size_t)b * (G3 + 1));
        pfr[(size_t)b * NF + qi] = r;
    } else if (bx < 512) {
        int k  = (bx - 256) * BT + tid;    // sorted tgt points
        int b  = k >> 13, kl = k & 8191;
        int sg = 2 + b;                    // fine grid
        float4 qp = spts[(size_t)b * 8192 + kl];
        int    qi = sjall[(size_t)b * 8192 + kl];
        u64 r = grid_nn<false>(qp, spts + (size_t)sg * 8192, sjall + (size_t)sg * 8192,
                               ofsall + (size_t)sg * (G3 + 1));
        pfc[(size_t)b * MT + qi] = (unsigned)r;
    } else if (bx < 768) {
        int i = bx - 512;
        int chunk = i & 15, yb = (i >> 4) & 7, b = i >> 7;
        pairmin_val(coarse, tgtp, NC, MT/2, b, yb*BT, chunk*256, 256,
                    chunk, B_*NC, pcr);
    } else {
        int i = bx - 768;
        int yb = i & 127, b = i >> 7;
        pairmin_val(tgt, coarsep, MT, NC/2, b, yb*BT, 0, 256,
                    0, B_*MT, pcc);
    }
}

// ---------------------------------------------------------------------------
// tail_all (unchanged from R8 — verified): gather + stats + wedge volumes +
// reductions + last-block final combine.
// ---------------------------------------------------------------------------
__global__ __launch_bounds__(TPB) void tail_all(
    const float* __restrict__ fine, const float* __restrict__ tgt,
    const u64* __restrict__ pfr, const unsigned* __restrict__ pfc,
    const unsigned* __restrict__ pcr, const unsigned* __restrict__ pcc,
    double* __restrict__ bs, unsigned* __restrict__ counter,
    float* __restrict__ out)
{
    __shared__ float sp[TPB + 2][3], yp[TPB + 2][3];
    __shared__ double redw[4][9];
    __shared__ double lred[4][13];
    __shared__ int lastflag;
    const int bx = blockIdx.x, tid = threadIdx.x;
    const int wave = tid >> 6, lane = tid & 63;

    double v_s = 0, v_d2f = 0, v_d1c = 0, v_d2c = 0, v_yd2 = 0, v_zs = 0, v_zt = 0;
    double vs = 0, vt = 0;
    int role_b = 0;

    if (bx < 64) {                              // ---- fine-rows ----
        const int base = bx * TPB;
        const int g = base + tid;
        const int b = base >> 13;  role_b = b;
        u64 best = pfr[g];
        float d1 = __uint_as_float((unsigned)(best >> 32));
        int idx  = (int)(best & 0xffffffffULL);
        float s = sqrtf(fmaxf(d1, 1e-12f));
        const float* y  = tgt  + ((size_t)b * MT + idx) * 3;
        const float* sr = fine + (size_t)g * 3;
        float y0 = y[0],  y1 = y[1],  y2 = y[2];
        float s0 = sr[0], s1 = sr[1], s2 = sr[2];
        yp[tid][0] = y0; yp[tid][1] = y1; yp[tid][2] = y2;
        sp[tid][0] = s0; sp[tid][1] = s1; sp[tid][2] = s2;
        const int base_b = base & (NF - 1);
        if (tid < 2 && base_b + TPB + tid < NF) {        // halo rows
            int g2 = base + TPB + tid;
            u64 b2 = pfr[g2];
            int i2 = (int)(b2 & 0xffffffffULL);
            const float* yh = tgt  + ((size_t)b * MT + i2) * 3;
            const float* sh = fine + (size_t)g2 * 3;
            #pragma unroll
            for (int k = 0; k < 3; ++k) { yp[TPB + tid][k] = yh[k]; sp[TPB + tid][k] = sh[k]; }
        }
        __syncthreads();
        v_s = s;
        float yd = s1 - y1;
        v_yd2 = (double)(yd * yd);
        v_zs  = (double)(s2 * s2);
        v_zt  = (double)(y2 * y2);
        int rb = base_b + tid;
        if (rb <= NF - 3) {          // same f32 exprs as the verified R3 kernel
            {
                const float* a = sp[tid]; const float* c = sp[tid+1]; const float* e = sp[tid+2];
                float c0 = a[1]*c[2] - a[2]*c[1];
                float c1 = a[2]*c[0] - a[0]*c[2];
                float c2 = a[0]*c[1] - a[1]*c[0];
                vs = (double)(c0*e[0] + c1*e[1] + c2*e[2]);
            }
            {
                const float* a = yp[tid]; const float* c = yp[tid+1]; const float* e = yp[tid+2];
                float c0 = a[1]*c[2] - a[2]*c[1];
                float c1 = a[2]*c[0] - a[0]*c[2];
                float c2 = a[0]*c[1] - a[1]*c[0];
                vt = (double)(c0*e[0] + c1*e[1] + c2*e[2]);
            }
        }
    } else if (bx < 128) {                      // ---- fine-cols ----
        const int g = (bx - 64) * TPB + tid;
        v_d2f = (double)sqrtf(fmaxf(__uint_as_float(pfc[g]), 1e-12f));
    } else if (bx < 132) {                      // ---- coarse-rows ----
        const int g = (bx - 128) * TPB + tid;
        unsigned best = pcr[g];
        #pragma unroll
        for (int c = 1; c < CF; ++c) best = min(best, pcr[(size_t)c * (B_ * NC) + g]);
        v_d1c = (double)sqrtf(fmaxf(__uint_as_float(best), 1e-12f));
    } else {                                    // ---- coarse-cols ----
        const int g = (bx - 132) * TPB + tid;
        v_d2c = (double)sqrtf(fmaxf(__uint_as_float(pcc[g]), 1e-12f));
    }

    double r9[9] = {v_s, v_d2f, v_d1c, v_d2c, v_yd2, v_zs, v_zt, vs, vt};
    for (int o = 32; o; o >>= 1) {
        #pragma unroll
        for (int k = 0; k < 9; ++k) r9[k] += __shfl_down(r9[k], o);
    }
    if (lane == 0) {
        #pragma unroll
        for (int k = 0; k < 9; ++k) redw[wave][k] = r9[k];
    }
    __syncthreads();
    if (tid == 0) {
        double t9[9];
        #pragma unroll
        for (int k = 0; k < 9; ++k)
            t9[k] = redw[0][k] + redw[1][k] + redw[2][k] + redw[3][k];
        double* o = bs + (size_t)bx * 16;
        #pragma unroll
        for (int k = 0; k < 16; ++k) o[k] = 0.0;
        o[0] = t9[0]; o[1] = t9[1]; o[2] = t9[2]; o[3] = t9[3]; o[4] = t9[4];
        o[5 + role_b]  = t9[5];
        o[7 + role_b]  = t9[6];
        o[9 + role_b]  = t9[7];
        o[11 + role_b] = t9[8];
        __threadfence();
        unsigned old = atomicAdd(counter, 1u);
        lastflag = (old == TAIL_BLOCKS - 1);
    }
    __syncthreads();
    if (!lastflag) return;

    __threadfence();
    double c13[13];
    if (tid < TAIL_BLOCKS) {
        const double* p = bs + (size_t)tid * 16;
        #pragma unroll
        for (int k = 0; k < 13; ++k) c13[k] = p[k];
    } else {
        #pragma unroll
        for (int k = 0; k < 13; ++k) c13[k] = 0.0;
    }
    for (int o = 32; o; o >>= 1) {
        #pragma unroll
        for (int k = 0; k < 13; ++k) c13[k] += __shfl_down(c13[k], o);
    }
    if (lane == 0) {
        #pragma unroll
        for (int k = 0; k < 13; ++k) lred[wave][k] = c13[k];
    }
    __syncthreads();
    if (tid == 0) {
        double S[13];
        #pragma unroll
        for (int k = 0; k < 13; ++k)
            S[k] = lred[0][k] + lred[1][k] + lred[2][k] + lred[3][k];
        double m_d1f = S[0] / (double)(B_ * NF);
        double m_d2f = S[1] / (double)(B_ * MT);
        double m_d1c = S[2] / (double)(B_ * NC);
        double m_d2c = S[3] / (double)(B_ * MT);
        double loss_align_fine   = 0.5 * (m_d1f + m_d2f);
        double loss_align_coarse = 0.5 * (m_d1c + m_d2c);
        double loss_ref = S[4] / (double)(B_ * NF);
        double loss_rot = 0.0, loss_geo = 0.0;
        for (int b = 0; b < B_; ++b) {
            double dn = sqrt(S[5 + b]) - sqrt(S[7 + b]);
            loss_rot += dn * dn;
            double dv = (S[9 + b] - S[11 + b]) / 6.0;
            loss_geo += dv * dv;
        }
        loss_rot /= (double)B_;
        loss_geo /= (double)B_;
        out[0] = (float)(loss_rot + loss_ref + loss_align_coarse + loss_align_fine + loss_geo);
    }
}

extern "C" void kernel_launch(void* const* d_in, const int* in_sizes, int n_in,
                              void* d_out, int out_size, void* d_ws, size_t ws_size,
                              hipStream_t stream)
{
    const float* src_coarse = (const float*)d_in[0];
    const float* src_fine   = (const float*)d_in[1];
    const float* tgt        = (const float*)d_in[2];
    float* out = (float*)d_out;
    char*  ws  = (char*)d_ws;

    // ws layout (bytes) — identical to R8 (verified). Everything written
    // before read; brute prefetch overruns (<=32B) land in the next region.
    //   [0,       131072)  u64 pfr[16384]
    //   [131072,  196608)  u32 pfc[16384]
    //   [196608,  262144)  u32 pcr[16][1024]
    //   [262144,  327680)  u32 pcc[16384]
    //   [327680,  589824)  float tgtp[8192*8]
    //   [589824,  606208)  float coarsep[512*8]
    //   [606208,  1130496) float4 spts[4][8192]
    //   [1130496, 1261568) int sj[4][8192]
    //   [1261568, 1482768) int ofs[4][G3+1]
    //   [1482768, 1613840) int pcell[4][8192]
    //   [1613840, 1638928) double bs[196][16]
    //   [1638928, 1638932) u32 counter
    u64*      pfr     = (u64*)(ws);
    unsigned* pfc     = (unsigned*)(ws + 131072);
    unsigned* pcr     = (unsigned*)(ws + 196608);
    unsigned* pcc     = (unsigned*)(ws + 262144);
    float*    tgtp    = (float*)(ws + 327680);
    float*    coarsep = (float*)(ws + 589824);
    float4*   spts    = (float4*)(ws + 606208);
    int*      sjall   = (int*)(ws + 1130496);
    int*      ofsall  = (int*)(ws + 1261568);
    int*      pcell   = (int*)(ws + 1482768);
    double*   bs      = (double*)(ws + 1613840);
    unsigned* counter = (unsigned*)(ws + 1638928);

    prep_build<<<dim3(12), 1024, 0, stream>>>(
        src_coarse, src_fine, tgt, spts, sjall, ofsall, pcell,
        tgtp, coarsep, counter);
    pair_all<<<dim3(1024), BT, 0, stream>>>(
        src_coarse, tgt, spts, sjall, ofsall,
        (const v2f*)tgtp, (const v2f*)coarsep, pfr, pfc, pcr, pcc);
    tail_all<<<dim3(TAIL_BLOCKS), TPB, 0, stream>>>(
        src_fine, tgt, pfr, pfc, pcr, pcc, bs, counter, out);
}